// Round 15
// baseline (75.970 us; speedup 1.0000x reference)
//
#include <hip/hip_runtime.h>

#define N_NODES 100000
#define DEG 16
#define N_EDGES (N_NODES * DEG)
#define NT 64                              // nodes per k_ab / k_edge block
#define NBLK2 ((N_NODES + NT - 1) / NT)    // 1563 blocks
#define FSP 68

// ---------------------------------------------------------------------------
// Kernel 1 (round-9 v7 body; ws staged directly from w0 -> k_prep deleted):
//   AB[n][0:64]   = W0[:,0:64]  @ f[n] + b0
//   AB[n][64:128] = W0[:,64:128]@ f[n]
// tile = 64 nodes x 128 outs, 256 thr; thread = 4 nodes x (A-quad + B-quad).
// LDS = ws[32][128] K-half (16 KB) + fs[64][68] (17.4 KB) = 33.8 KB.
// ws[k][o] = (o<64) ? w0[o][h*32+k] : w0[o-64][64+h*32+k]  (scalar gather,
// w0 = 33 KB L1/L2-hot; measured equivalent to w0T staging in round 2).
// Chain per (n,o): k ascending 0..63 fmaf, +b0 after -> AB bit-identical.
// ---------------------------------------------------------------------------
__global__ __launch_bounds__(256) void k_ab(const float* __restrict__ feat,
                                            const float* __restrict__ w0,
                                            const float* __restrict__ b0,
                                            float* __restrict__ AB) {
    __shared__ float ws[32][128];
    __shared__ float fs[64][FSP];
    const int tid = threadIdx.x;
    const int n0 = blockIdx.x * NT;
    const int to = tid & 15;   // quadA outs to*4..+3, quadB outs 64+to*4..+3
    const int tn = tid >> 4;   // nodes tn*4..tn*4+3 (of tile)

    for (int idx = tid; idx < 1024; idx += 256) {      // feat tile 64x64
        int r = idx >> 4, k4 = idx & 15;
        int n = n0 + r;
        float4 v = make_float4(0.f, 0.f, 0.f, 0.f);
        if (n < N_NODES) v = *(const float4*)(feat + (size_t)n * 64 + k4 * 4);
        *(float4*)&fs[r][k4 * 4] = v;
    }
#define STAGE_WS(H)                                                     \
    for (int idx = tid; idx < 4096; idx += 256) {                       \
        int k = idx >> 7, o = idx & 127;                                \
        ws[k][o] = (o < 64) ? w0[o * 129 + (H) * 32 + k]                \
                            : w0[(o - 64) * 129 + 64 + (H) * 32 + k];   \
    }
    STAGE_WS(0)
    __syncthreads();

#define FMAQ(A, Q, F4, W0, W1, W2, W3)                        \
    acc[A][Q][0] = fmaf(F4.x, W0.x, acc[A][Q][0]);            \
    acc[A][Q][1] = fmaf(F4.x, W0.y, acc[A][Q][1]);            \
    acc[A][Q][2] = fmaf(F4.x, W0.z, acc[A][Q][2]);            \
    acc[A][Q][3] = fmaf(F4.x, W0.w, acc[A][Q][3]);            \
    acc[A][Q][0] = fmaf(F4.y, W1.x, acc[A][Q][0]);            \
    acc[A][Q][1] = fmaf(F4.y, W1.y, acc[A][Q][1]);            \
    acc[A][Q][2] = fmaf(F4.y, W1.z, acc[A][Q][2]);            \
    acc[A][Q][3] = fmaf(F4.y, W1.w, acc[A][Q][3]);            \
    acc[A][Q][0] = fmaf(F4.z, W2.x, acc[A][Q][0]);            \
    acc[A][Q][1] = fmaf(F4.z, W2.y, acc[A][Q][1]);            \
    acc[A][Q][2] = fmaf(F4.z, W2.z, acc[A][Q][2]);            \
    acc[A][Q][3] = fmaf(F4.z, W2.w, acc[A][Q][3]);            \
    acc[A][Q][0] = fmaf(F4.w, W3.x, acc[A][Q][0]);            \
    acc[A][Q][1] = fmaf(F4.w, W3.y, acc[A][Q][1]);            \
    acc[A][Q][2] = fmaf(F4.w, W3.z, acc[A][Q][2]);            \
    acc[A][Q][3] = fmaf(F4.w, W3.w, acc[A][Q][3]);
#define FMAROW(A)                                             \
    {                                                         \
        float4 f4 = *(const float4*)&fs[tn * 4 + (A)][h * 32 + kk]; \
        FMAQ(A, 0, f4, w0a, w1a, w2a, w3a)                    \
        FMAQ(A, 1, f4, w0b, w1b, w2b, w3b)                    \
    }

    float acc[4][2][4];
#pragma unroll
    for (int a = 0; a < 4; ++a)
#pragma unroll
        for (int q = 0; q < 2; ++q)
#pragma unroll
            for (int j = 0; j < 4; ++j) acc[a][q][j] = 0.f;

#pragma unroll 1
    for (int h = 0; h < 2; ++h) {
        if (h == 1) {                                  // restage ws: K rows 32..63
            __syncthreads();
            STAGE_WS(1)
            __syncthreads();
        }
#pragma unroll
        for (int k4 = 0; k4 < 8; ++k4) {
            const int kk = k4 * 4;
            float4 w0a = *(const float4*)&ws[kk + 0][to * 4];
            float4 w0b = *(const float4*)&ws[kk + 0][64 + to * 4];
            float4 w1a = *(const float4*)&ws[kk + 1][to * 4];
            float4 w1b = *(const float4*)&ws[kk + 1][64 + to * 4];
            float4 w2a = *(const float4*)&ws[kk + 2][to * 4];
            float4 w2b = *(const float4*)&ws[kk + 2][64 + to * 4];
            float4 w3a = *(const float4*)&ws[kk + 3][to * 4];
            float4 w3b = *(const float4*)&ws[kk + 3][64 + to * 4];
            FMAROW(0) FMAROW(1) FMAROW(2) FMAROW(3)
        }
    }
    float4 bb = *(const float4*)(b0 + to * 4);    // b0 folds into A-quad only
#pragma unroll
    for (int a = 0; a < 4; ++a) {
        int n = n0 + tn * 4 + a;
        if (n < N_NODES) {
            float4 oa = make_float4(acc[a][0][0] + bb.x, acc[a][0][1] + bb.y,
                                    acc[a][0][2] + bb.z, acc[a][0][3] + bb.w);
            float4 ob = make_float4(acc[a][1][0], acc[a][1][1],
                                    acc[a][1][2], acc[a][1][3]);
            *(float4*)(AB + (size_t)n * 128 + to * 4) = oa;
            *(float4*)(AB + (size_t)n * 128 + 64 + to * 4) = ob;
        }
    }
#undef FMAROW
#undef FMAQ
#undef STAGE_WS
}

// ---------------------------------------------------------------------------
// Kernel 2 (round-9 v3 verbatim): B staged in LDS, A read per-q from global
// (4-lane L1 broadcast). LDS ~22.3 KB. z chain bit-identical.
// ---------------------------------------------------------------------------
__global__ __launch_bounds__(256) void k_edge(const float* __restrict__ AB,
                                              const float* __restrict__ values,
                                              const int* __restrict__ indices,
                                              const float* __restrict__ w0,
                                              const float* __restrict__ w1,
                                              const float* __restrict__ b1,
                                              float* __restrict__ z,
                                              double* __restrict__ partial) {
    __shared__ float b_s[80][FSP];
    __shared__ float wv_s[64];
    __shared__ float w1_s[64];
    __shared__ double redw[4];
    const int t = threadIdx.x;
    const int n0 = blockIdx.x * NT;
    const int nvalid = min(NT, N_NODES - n0);

    if (t < 64) {
        wv_s[t] = w0[t * 129 + 128];
        w1_s[t] = w1[t];
    }
    for (int idx = t; idx < 1280; idx += 256) {        // B: 80 rows x 16 float4
        int r = idx >> 4, k4 = idx & 15;
        int node = n0 + 1 + r;
        if (node >= N_NODES) node -= N_NODES;
        *(float4*)&b_s[r][k4 * 4] = *(const float4*)(AB + (size_t)node * 128 + 64 + k4 * 4);
    }
    __syncthreads();

    const int row = t >> 2;
    const bool ok = row < nvalid;
    double ss = 0.0;
    if (ok) {
        const float* Ap = AB + (size_t)(n0 + row) * 128;   // L1-broadcast reads
        const int ebase = n0 * 16 + (t << 2);
        int4   c4 = *(const int4*)(indices + N_EDGES + ebase);
        float4 v4 = *(const float4*)(values + ebase);
        int   cols[4] = {c4.x, c4.y, c4.z, c4.w};
        float vv[4]   = {v4.x, v4.y, v4.z, v4.w};
        int   ii[4];
        bool  fb[4];
        bool  anyfb = false;
#pragma unroll
        for (int k = 0; k < 4; ++k) {
            int i = cols[k] - (n0 + 1);
            if (i < 0) i += N_NODES;
            fb[k] = (i >= 80);
            anyfb |= fb[k];
            ii[k] = fb[k] ? 0 : i;
        }
        float acc[4] = {0.f, 0.f, 0.f, 0.f};
#pragma unroll
        for (int q = 0; q < 16; ++q) {
            float4 a4  = *(const float4*)(Ap + q * 4);
            float4 wv4 = *(const float4*)&wv_s[q * 4];
            float4 w14 = *(const float4*)&w1_s[q * 4];
#pragma unroll
            for (int k = 0; k < 4; ++k) {
                float4 b4 = *(const float4*)&b_s[ii[k]][q * 4];
                float t0 = fmaf(wv4.x, vv[k], a4.x + b4.x);
                float t1 = fmaf(wv4.y, vv[k], a4.y + b4.y);
                float t2 = fmaf(wv4.z, vv[k], a4.z + b4.z);
                float t3 = fmaf(wv4.w, vv[k], a4.w + b4.w);
                acc[k] = fmaf(w14.x, fmaxf(t0, 0.f), acc[k]);
                acc[k] = fmaf(w14.y, fmaxf(t1, 0.f), acc[k]);
                acc[k] = fmaf(w14.z, fmaxf(t2, 0.f), acc[k]);
                acc[k] = fmaf(w14.w, fmaxf(t3, 0.f), acc[k]);
            }
        }
        if (anyfb) {            // never taken for this graph; correctness net
#pragma unroll
            for (int k = 0; k < 4; ++k) {
                if (fb[k]) {
                    const float* Bp = AB + (size_t)cols[k] * 128 + 64;
                    float a = 0.f;
                    for (int h = 0; h < 64; ++h) {
                        float th = fmaf(wv_s[h], vv[k], Ap[h] + Bp[h]);
                        a = fmaf(w1_s[h], fmaxf(th, 0.f), a);
                    }
                    acc[k] = a;
                }
            }
        }
        const float b1v = b1[0];
        float4 z4;
        z4.x = acc[0] + b1v; z4.y = acc[1] + b1v;
        z4.z = acc[2] + b1v; z4.w = acc[3] + b1v;
        *(float4*)(z + ebase) = z4;
        ss = (double)z4.x * z4.x + (double)z4.y * z4.y +
             (double)z4.z * z4.z + (double)z4.w * z4.w;
    }
    // deterministic wave shuffle reduce (fp64), then 4 partials -> block sum
#pragma unroll
    for (int off = 32; off > 0; off >>= 1) ss += __shfl_down(ss, off, 64);
    if ((t & 63) == 0) redw[t >> 6] = ss;
    __syncthreads();
    if (t == 0) partial[blockIdx.x] = (redw[0] + redw[1]) + (redw[2] + redw[3]);
}

// ---------------------------------------------------------------------------
// Kernel 3 (k_norm + k_mask merged): every block redundantly performs the
// EXACT k_norm traversal (per-thread strided sum over 1563 partials + tree
// reduce) -> bit-identical nrm in all blocks; then the round-2 mask body.
// Inactive tail threads stay for the barriers.
// ---------------------------------------------------------------------------
__global__ __launch_bounds__(256) void k_mask(const float* __restrict__ z,
                                              const float* __restrict__ gumbel,
                                              const double* __restrict__ partial,
                                              const int* __restrict__ temperature,
                                              float* __restrict__ out) {
    __shared__ double red[256];
    const int t = threadIdx.x;
    {
        double s = 0.0;
        for (int i = t; i < NBLK2; i += 256) s += partial[i];
        red[t] = s;
        __syncthreads();
#pragma unroll
        for (int off = 128; off > 0; off >>= 1) {
            if (t < off) red[t] += red[t + off];
            __syncthreads();
        }
    }
    const double nv = fmax(sqrt(red[0]), 1e-12);

    const int n = blockIdx.x * 256 + t;
    if (n >= N_NODES) return;
    const double inv_nv = 1.0 / nv;
    const double invT = 1.0 / (double)temperature[0];
    const float4* z4 = (const float4*)(z + (size_t)n * 16);
    const float4* g4 = (const float4*)(gumbel + (size_t)n * 16);
    double tl[16], y[16];
#pragma unroll
    for (int q = 0; q < 4; ++q) {
        float4 zv = z4[q];
        float4 gv = g4[q];
        tl[q * 4 + 0] = ((double)zv.x * inv_nv + (double)gv.x) * invT;
        tl[q * 4 + 1] = ((double)zv.y * inv_nv + (double)gv.y) * invT;
        tl[q * 4 + 2] = ((double)zv.z * inv_nv + (double)gv.z) * invT;
        tl[q * 4 + 3] = ((double)zv.w * inv_nv + (double)gv.w) * invT;
    }
    double m = tl[0];
#pragma unroll
    for (int i = 1; i < 16; ++i) m = fmax(m, tl[i]);
    double s = 0.0;
#pragma unroll
    for (int i = 0; i < 16; ++i) { y[i] = exp(tl[i] - m); s += y[i]; }
    const double inv_s = 1.0 / s;
#pragma unroll
    for (int i = 0; i < 16; ++i) y[i] *= inv_s;
    double thre = y[0];
#pragma unroll
    for (int i = 0; i < 16; ++i) {
        int c = 0, q = 0;
#pragma unroll
        for (int j = 0; j < 16; ++j) {
            c += (y[j] > y[i]) ? 1 : 0;
            q += (y[j] == y[i]) ? 1 : 0;
        }
        if (c <= 7 && 7 < c + q) thre = y[i];
    }
    float4* o4 = (float4*)(out + (size_t)n * 16);
#pragma unroll
    for (int qq = 0; qq < 4; ++qq) {
        float4 ov;
        ov.x = ((y[qq * 4 + 0] - thre + 1e-12) > 0.0) ? (float)y[qq * 4 + 0] : 0.f;
        ov.y = ((y[qq * 4 + 1] - thre + 1e-12) > 0.0) ? (float)y[qq * 4 + 1] : 0.f;
        ov.z = ((y[qq * 4 + 2] - thre + 1e-12) > 0.0) ? (float)y[qq * 4 + 2] : 0.f;
        ov.w = ((y[qq * 4 + 3] - thre + 1e-12) > 0.0) ? (float)y[qq * 4 + 3] : 0.f;
        o4[qq] = ov;
    }
}

// ---------------------------------------------------------------------------
extern "C" void kernel_launch(void* const* d_in, const int* in_sizes, int n_in,
                              void* d_out, int out_size, void* d_ws, size_t ws_size,
                              hipStream_t stream) {
    const float* feat    = (const float*)d_in[0];   // [N,64]
    const float* values  = (const float*)d_in[1];   // [E]
    const float* w0      = (const float*)d_in[2];   // [64,129]
    const float* b0      = (const float*)d_in[3];   // [64]
    const float* w1      = (const float*)d_in[4];   // [1,64]
    const float* b1      = (const float*)d_in[5];   // [1]
    const float* gumbel  = (const float*)d_in[6];   // [E]
    const int*   indices = (const int*)d_in[7];     // [2,E]
    const int*   temp    = (const int*)d_in[9];     // scalar
    float* out = (float*)d_out;

    // workspace: AB 51.2MB | z 6.4MB | partial (1563 doubles)
    float*  AB      = (float*)d_ws;
    float*  zbuf    = (float*)((char*)d_ws + (size_t)N_NODES * 128 * 4);
    double* partial = (double*)((char*)d_ws + (size_t)N_NODES * 128 * 4
                                + (size_t)N_EDGES * 4);

    k_ab  <<<NBLK2, 256, 0, stream>>>(feat, w0, b0, AB);
    k_edge<<<NBLK2, 256, 0, stream>>>(AB, values, indices, w0, w1, b1, zbuf, partial);
    k_mask<<<(N_NODES + 255) / 256, 256, 0, stream>>>(zbuf, gumbel, partial, temp, out);
}

// Round 16
// 72.783 us; speedup vs baseline: 1.0438x; 1.0438x over previous
//
#include <hip/hip_runtime.h>

#define N_NODES 100000
#define DEG 16
#define N_EDGES (N_NODES * DEG)
#define NT 64                              // nodes per k_ab / k_edge block
#define NBLK2 ((N_NODES + NT - 1) / NT)    // 1563 blocks
#define FSP 68

// ---------------------------------------------------------------------------
// Prep: w0T[k][o] = A/B-split transpose of w0:
//   o <  64 : w0[o][k]        (A-part: weight for hidden o, input k)
//   o >= 64 : w0[o-64][64+k]  (B-part: weight for hidden o-64, input 64+k)
// 32 KB, L2-resident; makes k_ab's W staging coalesced (round-15 lesson:
// staging from w0 directly = stride-516B scalar gather, +10us).
// ---------------------------------------------------------------------------
__global__ __launch_bounds__(256) void k_prep(const float* __restrict__ w0,
                                              float* __restrict__ w0T) {
    int id = blockIdx.x * 256 + threadIdx.x;
    if (id < 64 * 128) {
        int k = id >> 7, o = id & 127;
        w0T[k * 128 + o] = (o < 64) ? w0[o * 129 + k]
                                    : w0[(o - 64) * 129 + 64 + k];
    }
}

// ---------------------------------------------------------------------------
// Kernel 1 (round-9 v7 verbatim — measured best at 39.8us):
// tile = 64 nodes x 128 outs, 256 thr; thread = 4 nodes x (A-quad + B-quad).
// LDS = ws[32][128] K-half (16 KB, float4-staged from w0T) + fs[64][68].
// Chain per (n,o): k ascending 0..63 fmaf, +b0 after -> AB bit-identical.
// ---------------------------------------------------------------------------
__global__ __launch_bounds__(256) void k_ab(const float* __restrict__ feat,
                                            const float* __restrict__ w0T,
                                            const float* __restrict__ b0,
                                            float* __restrict__ AB) {
    __shared__ float ws[32][128];
    __shared__ float fs[64][FSP];
    const int tid = threadIdx.x;
    const int n0 = blockIdx.x * NT;
    const int to = tid & 15;   // quadA outs to*4..+3, quadB outs 64+to*4..+3
    const int tn = tid >> 4;   // nodes tn*4..tn*4+3 (of tile)

    for (int idx = tid; idx < 1024; idx += 256) {      // feat tile 64x64
        int r = idx >> 4, k4 = idx & 15;
        int n = n0 + r;
        float4 v = make_float4(0.f, 0.f, 0.f, 0.f);
        if (n < N_NODES) v = *(const float4*)(feat + (size_t)n * 64 + k4 * 4);
        *(float4*)&fs[r][k4 * 4] = v;
    }
    for (int idx = tid; idx < 1024; idx += 256) {      // ws: K rows 0..31
        int k = idx >> 5, o4 = idx & 31;
        *(float4*)&ws[k][o4 * 4] = *(const float4*)&w0T[k * 128 + o4 * 4];
    }
    __syncthreads();

#define FMAQ(A, Q, F4, W0, W1, W2, W3)                        \
    acc[A][Q][0] = fmaf(F4.x, W0.x, acc[A][Q][0]);            \
    acc[A][Q][1] = fmaf(F4.x, W0.y, acc[A][Q][1]);            \
    acc[A][Q][2] = fmaf(F4.x, W0.z, acc[A][Q][2]);            \
    acc[A][Q][3] = fmaf(F4.x, W0.w, acc[A][Q][3]);            \
    acc[A][Q][0] = fmaf(F4.y, W1.x, acc[A][Q][0]);            \
    acc[A][Q][1] = fmaf(F4.y, W1.y, acc[A][Q][1]);            \
    acc[A][Q][2] = fmaf(F4.y, W1.z, acc[A][Q][2]);            \
    acc[A][Q][3] = fmaf(F4.y, W1.w, acc[A][Q][3]);            \
    acc[A][Q][0] = fmaf(F4.z, W2.x, acc[A][Q][0]);            \
    acc[A][Q][1] = fmaf(F4.z, W2.y, acc[A][Q][1]);            \
    acc[A][Q][2] = fmaf(F4.z, W2.z, acc[A][Q][2]);            \
    acc[A][Q][3] = fmaf(F4.z, W2.w, acc[A][Q][3]);            \
    acc[A][Q][0] = fmaf(F4.w, W3.x, acc[A][Q][0]);            \
    acc[A][Q][1] = fmaf(F4.w, W3.y, acc[A][Q][1]);            \
    acc[A][Q][2] = fmaf(F4.w, W3.z, acc[A][Q][2]);            \
    acc[A][Q][3] = fmaf(F4.w, W3.w, acc[A][Q][3]);
#define FMAROW(A)                                             \
    {                                                         \
        float4 f4 = *(const float4*)&fs[tn * 4 + (A)][h * 32 + kk]; \
        FMAQ(A, 0, f4, w0a, w1a, w2a, w3a)                    \
        FMAQ(A, 1, f4, w0b, w1b, w2b, w3b)                    \
    }

    float acc[4][2][4];
#pragma unroll
    for (int a = 0; a < 4; ++a)
#pragma unroll
        for (int q = 0; q < 2; ++q)
#pragma unroll
            for (int j = 0; j < 4; ++j) acc[a][q][j] = 0.f;

#pragma unroll 1
    for (int h = 0; h < 2; ++h) {
        if (h == 1) {                                  // restage ws: K rows 32..63
            __syncthreads();
            for (int idx = tid; idx < 1024; idx += 256) {
                int k = idx >> 5, o4 = idx & 31;
                *(float4*)&ws[k][o4 * 4] =
                    *(const float4*)&w0T[(32 + k) * 128 + o4 * 4];
            }
            __syncthreads();
        }
#pragma unroll
        for (int k4 = 0; k4 < 8; ++k4) {
            const int kk = k4 * 4;
            float4 w0a = *(const float4*)&ws[kk + 0][to * 4];
            float4 w0b = *(const float4*)&ws[kk + 0][64 + to * 4];
            float4 w1a = *(const float4*)&ws[kk + 1][to * 4];
            float4 w1b = *(const float4*)&ws[kk + 1][64 + to * 4];
            float4 w2a = *(const float4*)&ws[kk + 2][to * 4];
            float4 w2b = *(const float4*)&ws[kk + 2][64 + to * 4];
            float4 w3a = *(const float4*)&ws[kk + 3][to * 4];
            float4 w3b = *(const float4*)&ws[kk + 3][64 + to * 4];
            FMAROW(0) FMAROW(1) FMAROW(2) FMAROW(3)
        }
    }
    float4 bb = *(const float4*)(b0 + to * 4);    // b0 folds into A-quad only
#pragma unroll
    for (int a = 0; a < 4; ++a) {
        int n = n0 + tn * 4 + a;
        if (n < N_NODES) {
            float4 oa = make_float4(acc[a][0][0] + bb.x, acc[a][0][1] + bb.y,
                                    acc[a][0][2] + bb.z, acc[a][0][3] + bb.w);
            float4 ob = make_float4(acc[a][1][0], acc[a][1][1],
                                    acc[a][1][2], acc[a][1][3]);
            *(float4*)(AB + (size_t)n * 128 + to * 4) = oa;
            *(float4*)(AB + (size_t)n * 128 + 64 + to * 4) = ob;
        }
    }
#undef FMAROW
#undef FMAQ
}

// ---------------------------------------------------------------------------
// Kernel 2 (round-9 v3 verbatim): B staged in LDS, A read per-q from global
// (4-lane L1 broadcast). LDS ~22.3 KB. z chain bit-identical.
// ---------------------------------------------------------------------------
__global__ __launch_bounds__(256) void k_edge(const float* __restrict__ AB,
                                              const float* __restrict__ values,
                                              const int* __restrict__ indices,
                                              const float* __restrict__ w0,
                                              const float* __restrict__ w1,
                                              const float* __restrict__ b1,
                                              float* __restrict__ z,
                                              double* __restrict__ partial) {
    __shared__ float b_s[80][FSP];
    __shared__ float wv_s[64];
    __shared__ float w1_s[64];
    __shared__ double redw[4];
    const int t = threadIdx.x;
    const int n0 = blockIdx.x * NT;
    const int nvalid = min(NT, N_NODES - n0);

    if (t < 64) {
        wv_s[t] = w0[t * 129 + 128];
        w1_s[t] = w1[t];
    }
    for (int idx = t; idx < 1280; idx += 256) {        // B: 80 rows x 16 float4
        int r = idx >> 4, k4 = idx & 15;
        int node = n0 + 1 + r;
        if (node >= N_NODES) node -= N_NODES;
        *(float4*)&b_s[r][k4 * 4] = *(const float4*)(AB + (size_t)node * 128 + 64 + k4 * 4);
    }
    __syncthreads();

    const int row = t >> 2;
    const bool ok = row < nvalid;
    double ss = 0.0;
    if (ok) {
        const float* Ap = AB + (size_t)(n0 + row) * 128;   // L1-broadcast reads
        const int ebase = n0 * 16 + (t << 2);
        int4   c4 = *(const int4*)(indices + N_EDGES + ebase);
        float4 v4 = *(const float4*)(values + ebase);
        int   cols[4] = {c4.x, c4.y, c4.z, c4.w};
        float vv[4]   = {v4.x, v4.y, v4.z, v4.w};
        int   ii[4];
        bool  fb[4];
        bool  anyfb = false;
#pragma unroll
        for (int k = 0; k < 4; ++k) {
            int i = cols[k] - (n0 + 1);
            if (i < 0) i += N_NODES;
            fb[k] = (i >= 80);
            anyfb |= fb[k];
            ii[k] = fb[k] ? 0 : i;
        }
        float acc[4] = {0.f, 0.f, 0.f, 0.f};
#pragma unroll
        for (int q = 0; q < 16; ++q) {
            float4 a4  = *(const float4*)(Ap + q * 4);
            float4 wv4 = *(const float4*)&wv_s[q * 4];
            float4 w14 = *(const float4*)&w1_s[q * 4];
#pragma unroll
            for (int k = 0; k < 4; ++k) {
                float4 b4 = *(const float4*)&b_s[ii[k]][q * 4];
                float t0 = fmaf(wv4.x, vv[k], a4.x + b4.x);
                float t1 = fmaf(wv4.y, vv[k], a4.y + b4.y);
                float t2 = fmaf(wv4.z, vv[k], a4.z + b4.z);
                float t3 = fmaf(wv4.w, vv[k], a4.w + b4.w);
                acc[k] = fmaf(w14.x, fmaxf(t0, 0.f), acc[k]);
                acc[k] = fmaf(w14.y, fmaxf(t1, 0.f), acc[k]);
                acc[k] = fmaf(w14.z, fmaxf(t2, 0.f), acc[k]);
                acc[k] = fmaf(w14.w, fmaxf(t3, 0.f), acc[k]);
            }
        }
        if (anyfb) {            // never taken for this graph; correctness net
#pragma unroll
            for (int k = 0; k < 4; ++k) {
                if (fb[k]) {
                    const float* Bp = AB + (size_t)cols[k] * 128 + 64;
                    float a = 0.f;
                    for (int h = 0; h < 64; ++h) {
                        float th = fmaf(wv_s[h], vv[k], Ap[h] + Bp[h]);
                        a = fmaf(w1_s[h], fmaxf(th, 0.f), a);
                    }
                    acc[k] = a;
                }
            }
        }
        const float b1v = b1[0];
        float4 z4;
        z4.x = acc[0] + b1v; z4.y = acc[1] + b1v;
        z4.z = acc[2] + b1v; z4.w = acc[3] + b1v;
        *(float4*)(z + ebase) = z4;
        ss = (double)z4.x * z4.x + (double)z4.y * z4.y +
             (double)z4.z * z4.z + (double)z4.w * z4.w;
    }
    // deterministic wave shuffle reduce (fp64), then 4 partials -> block sum
#pragma unroll
    for (int off = 32; off > 0; off >>= 1) ss += __shfl_down(ss, off, 64);
    if ((t & 63) == 0) redw[t >> 6] = ss;
    __syncthreads();
    if (t == 0) partial[blockIdx.x] = (redw[0] + redw[1]) + (redw[2] + redw[3]);
}

// ---------------------------------------------------------------------------
// Kernel 3 (norm inlined into mask — proven cheap in round 15): every block
// performs the EXACT k_norm traversal over the 1563 partials (bit-identical
// nrm in all blocks), then the round-2 mask body. Inactive tail threads stay
// for the barriers.
// ---------------------------------------------------------------------------
__global__ __launch_bounds__(256) void k_mask(const float* __restrict__ z,
                                              const float* __restrict__ gumbel,
                                              const double* __restrict__ partial,
                                              const int* __restrict__ temperature,
                                              float* __restrict__ out) {
    __shared__ double red[256];
    const int t = threadIdx.x;
    {
        double s = 0.0;
        for (int i = t; i < NBLK2; i += 256) s += partial[i];
        red[t] = s;
        __syncthreads();
#pragma unroll
        for (int off = 128; off > 0; off >>= 1) {
            if (t < off) red[t] += red[t + off];
            __syncthreads();
        }
    }
    const double nv = fmax(sqrt(red[0]), 1e-12);

    const int n = blockIdx.x * 256 + t;
    if (n >= N_NODES) return;
    const double inv_nv = 1.0 / nv;
    const double invT = 1.0 / (double)temperature[0];
    const float4* z4 = (const float4*)(z + (size_t)n * 16);
    const float4* g4 = (const float4*)(gumbel + (size_t)n * 16);
    double tl[16], y[16];
#pragma unroll
    for (int q = 0; q < 4; ++q) {
        float4 zv = z4[q];
        float4 gv = g4[q];
        tl[q * 4 + 0] = ((double)zv.x * inv_nv + (double)gv.x) * invT;
        tl[q * 4 + 1] = ((double)zv.y * inv_nv + (double)gv.y) * invT;
        tl[q * 4 + 2] = ((double)zv.z * inv_nv + (double)gv.z) * invT;
        tl[q * 4 + 3] = ((double)zv.w * inv_nv + (double)gv.w) * invT;
    }
    double m = tl[0];
#pragma unroll
    for (int i = 1; i < 16; ++i) m = fmax(m, tl[i]);
    double s = 0.0;
#pragma unroll
    for (int i = 0; i < 16; ++i) { y[i] = exp(tl[i] - m); s += y[i]; }
    const double inv_s = 1.0 / s;
#pragma unroll
    for (int i = 0; i < 16; ++i) y[i] *= inv_s;
    double thre = y[0];
#pragma unroll
    for (int i = 0; i < 16; ++i) {
        int c = 0, q = 0;
#pragma unroll
        for (int j = 0; j < 16; ++j) {
            c += (y[j] > y[i]) ? 1 : 0;
            q += (y[j] == y[i]) ? 1 : 0;
        }
        if (c <= 7 && 7 < c + q) thre = y[i];
    }
    float4* o4 = (float4*)(out + (size_t)n * 16);
#pragma unroll
    for (int qq = 0; qq < 4; ++qq) {
        float4 ov;
        ov.x = ((y[qq * 4 + 0] - thre + 1e-12) > 0.0) ? (float)y[qq * 4 + 0] : 0.f;
        ov.y = ((y[qq * 4 + 1] - thre + 1e-12) > 0.0) ? (float)y[qq * 4 + 1] : 0.f;
        ov.z = ((y[qq * 4 + 2] - thre + 1e-12) > 0.0) ? (float)y[qq * 4 + 2] : 0.f;
        ov.w = ((y[qq * 4 + 3] - thre + 1e-12) > 0.0) ? (float)y[qq * 4 + 3] : 0.f;
        o4[qq] = ov;
    }
}

// ---------------------------------------------------------------------------
extern "C" void kernel_launch(void* const* d_in, const int* in_sizes, int n_in,
                              void* d_out, int out_size, void* d_ws, size_t ws_size,
                              hipStream_t stream) {
    const float* feat    = (const float*)d_in[0];   // [N,64]
    const float* values  = (const float*)d_in[1];   // [E]
    const float* w0      = (const float*)d_in[2];   // [64,129]
    const float* b0      = (const float*)d_in[3];   // [64]
    const float* w1      = (const float*)d_in[4];   // [1,64]
    const float* b1      = (const float*)d_in[5];   // [1]
    const float* gumbel  = (const float*)d_in[6];   // [E]
    const int*   indices = (const int*)d_in[7];     // [2,E]
    const int*   temp    = (const int*)d_in[9];     // scalar
    float* out = (float*)d_out;

    // workspace: w0T 32KB | AB 51.2MB | z 6.4MB | partial (1563 doubles)
    float*  w0T     = (float*)d_ws;
    float*  AB      = (float*)((char*)d_ws + 64 * 128 * 4);
    float*  zbuf    = (float*)((char*)d_ws + 64 * 128 * 4 + (size_t)N_NODES * 128 * 4);
    double* partial = (double*)((char*)d_ws + 64 * 128 * 4 + (size_t)N_NODES * 128 * 4
                                + (size_t)N_EDGES * 4);

    k_prep<<<32, 256, 0, stream>>>(w0, w0T);
    k_ab  <<<NBLK2, 256, 0, stream>>>(feat, w0T, b0, AB);
    k_edge<<<NBLK2, 256, 0, stream>>>(AB, values, indices, w0, w1, b1, zbuf, partial);
    k_mask<<<(N_NODES + 255) / 256, 256, 0, stream>>>(zbuf, gumbel, partial, temp, out);
}

// Round 17
// 71.553 us; speedup vs baseline: 1.0617x; 1.0172x over previous
//
#include <hip/hip_runtime.h>

#define N_NODES 100000
#define DEG 16
#define N_EDGES (N_NODES * DEG)
#define NT 64                              // nodes per k_ab / k_edge block
#define NBLK2 ((N_NODES + NT - 1) / NT)    // 1563 blocks
#define FSP 68

// ---------------------------------------------------------------------------
// Prep: w0T[k][o] = A/B-split transpose of w0 (coalesced W staging for k_ab).
// ---------------------------------------------------------------------------
__global__ __launch_bounds__(256) void k_prep(const float* __restrict__ w0,
                                              float* __restrict__ w0T) {
    int id = blockIdx.x * 256 + threadIdx.x;
    if (id < 64 * 128) {
        int k = id >> 7, o = id & 127;
        w0T[k * 128 + o] = (o < 64) ? w0[o * 129 + k]
                                    : w0[(o - 64) * 129 + 64 + k];
    }
}

// ---------------------------------------------------------------------------
// Kernel 1 v12 — round-9 v7 tile at 512 threads (waves-per-CU experiment).
// Same 64-node x 128-out tile, same LDS (ws[32][128] K-half + fs[64][68] =
// 33.8 KB), but 8 waves share one LDS allocation instead of 4: if 2 blocks
// co-reside -> 16 waves/CU, 2x every previous k_ab configuration.
// Thread = 2 nodes x (A-quad to*4 + B-quad 64+to*4); acc[2][2][4] static.
// Wave patterns: fs rows stride 2*68 -> 4 distinct banks (free); ws quads
// 2-way (free). Chain per (n,o): k ascending 0..63, +b0 after ->
// AB bit-identical to all passing rounds.
// ---------------------------------------------------------------------------
__global__ __launch_bounds__(512) void k_ab(const float* __restrict__ feat,
                                            const float* __restrict__ w0T,
                                            const float* __restrict__ b0,
                                            float* __restrict__ AB) {
    __shared__ float ws[32][128];
    __shared__ float fs[64][FSP];
    const int tid = threadIdx.x;           // 0..511
    const int n0 = blockIdx.x * NT;
    const int to = tid & 15;   // quadA outs to*4..+3, quadB outs 64+to*4..+3
    const int tn = tid >> 4;   // 0..31; nodes tn*2, tn*2+1 (of tile)

    for (int idx = tid; idx < 1024; idx += 512) {      // feat tile 64x64
        int r = idx >> 4, k4 = idx & 15;
        int n = n0 + r;
        float4 v = make_float4(0.f, 0.f, 0.f, 0.f);
        if (n < N_NODES) v = *(const float4*)(feat + (size_t)n * 64 + k4 * 4);
        *(float4*)&fs[r][k4 * 4] = v;
    }
    for (int idx = tid; idx < 1024; idx += 512) {      // ws: K rows 0..31
        int k = idx >> 5, o4 = idx & 31;
        *(float4*)&ws[k][o4 * 4] = *(const float4*)&w0T[k * 128 + o4 * 4];
    }
    __syncthreads();

#define FMAQ(A, Q, F4, W0, W1, W2, W3)                        \
    acc[A][Q][0] = fmaf(F4.x, W0.x, acc[A][Q][0]);            \
    acc[A][Q][1] = fmaf(F4.x, W0.y, acc[A][Q][1]);            \
    acc[A][Q][2] = fmaf(F4.x, W0.z, acc[A][Q][2]);            \
    acc[A][Q][3] = fmaf(F4.x, W0.w, acc[A][Q][3]);            \
    acc[A][Q][0] = fmaf(F4.y, W1.x, acc[A][Q][0]);            \
    acc[A][Q][1] = fmaf(F4.y, W1.y, acc[A][Q][1]);            \
    acc[A][Q][2] = fmaf(F4.y, W1.z, acc[A][Q][2]);            \
    acc[A][Q][3] = fmaf(F4.y, W1.w, acc[A][Q][3]);            \
    acc[A][Q][0] = fmaf(F4.z, W2.x, acc[A][Q][0]);            \
    acc[A][Q][1] = fmaf(F4.z, W2.y, acc[A][Q][1]);            \
    acc[A][Q][2] = fmaf(F4.z, W2.z, acc[A][Q][2]);            \
    acc[A][Q][3] = fmaf(F4.z, W2.w, acc[A][Q][3]);            \
    acc[A][Q][0] = fmaf(F4.w, W3.x, acc[A][Q][0]);            \
    acc[A][Q][1] = fmaf(F4.w, W3.y, acc[A][Q][1]);            \
    acc[A][Q][2] = fmaf(F4.w, W3.z, acc[A][Q][2]);            \
    acc[A][Q][3] = fmaf(F4.w, W3.w, acc[A][Q][3]);
#define FMAROW(A)                                             \
    {                                                         \
        float4 f4 = *(const float4*)&fs[tn * 2 + (A)][h * 32 + kk]; \
        FMAQ(A, 0, f4, w0a, w1a, w2a, w3a)                    \
        FMAQ(A, 1, f4, w0b, w1b, w2b, w3b)                    \
    }

    float acc[2][2][4];
#pragma unroll
    for (int a = 0; a < 2; ++a)
#pragma unroll
        for (int q = 0; q < 2; ++q)
#pragma unroll
            for (int j = 0; j < 4; ++j) acc[a][q][j] = 0.f;

#pragma unroll 1
    for (int h = 0; h < 2; ++h) {
        if (h == 1) {                                  // restage ws: K rows 32..63
            __syncthreads();
            for (int idx = tid; idx < 1024; idx += 512) {
                int k = idx >> 5, o4 = idx & 31;
                *(float4*)&ws[k][o4 * 4] =
                    *(const float4*)&w0T[(32 + k) * 128 + o4 * 4];
            }
            __syncthreads();
        }
#pragma unroll
        for (int k4 = 0; k4 < 8; ++k4) {
            const int kk = k4 * 4;
            float4 w0a = *(const float4*)&ws[kk + 0][to * 4];
            float4 w0b = *(const float4*)&ws[kk + 0][64 + to * 4];
            float4 w1a = *(const float4*)&ws[kk + 1][to * 4];
            float4 w1b = *(const float4*)&ws[kk + 1][64 + to * 4];
            float4 w2a = *(const float4*)&ws[kk + 2][to * 4];
            float4 w2b = *(const float4*)&ws[kk + 2][64 + to * 4];
            float4 w3a = *(const float4*)&ws[kk + 3][to * 4];
            float4 w3b = *(const float4*)&ws[kk + 3][64 + to * 4];
            FMAROW(0) FMAROW(1)
        }
    }
    float4 bb = *(const float4*)(b0 + to * 4);    // b0 folds into A-quad only
#pragma unroll
    for (int a = 0; a < 2; ++a) {
        int n = n0 + tn * 2 + a;
        if (n < N_NODES) {
            float4 oa = make_float4(acc[a][0][0] + bb.x, acc[a][0][1] + bb.y,
                                    acc[a][0][2] + bb.z, acc[a][0][3] + bb.w);
            float4 ob = make_float4(acc[a][1][0], acc[a][1][1],
                                    acc[a][1][2], acc[a][1][3]);
            *(float4*)(AB + (size_t)n * 128 + to * 4) = oa;
            *(float4*)(AB + (size_t)n * 128 + 64 + to * 4) = ob;
        }
    }
#undef FMAROW
#undef FMAQ
}

// ---------------------------------------------------------------------------
// Kernel 2 (round-9 v3 verbatim): B staged in LDS, A read per-q from global
// (4-lane L1 broadcast). LDS ~22.3 KB. z chain bit-identical.
// ---------------------------------------------------------------------------
__global__ __launch_bounds__(256) void k_edge(const float* __restrict__ AB,
                                              const float* __restrict__ values,
                                              const int* __restrict__ indices,
                                              const float* __restrict__ w0,
                                              const float* __restrict__ w1,
                                              const float* __restrict__ b1,
                                              float* __restrict__ z,
                                              double* __restrict__ partial) {
    __shared__ float b_s[80][FSP];
    __shared__ float wv_s[64];
    __shared__ float w1_s[64];
    __shared__ double redw[4];
    const int t = threadIdx.x;
    const int n0 = blockIdx.x * NT;
    const int nvalid = min(NT, N_NODES - n0);

    if (t < 64) {
        wv_s[t] = w0[t * 129 + 128];
        w1_s[t] = w1[t];
    }
    for (int idx = t; idx < 1280; idx += 256) {        // B: 80 rows x 16 float4
        int r = idx >> 4, k4 = idx & 15;
        int node = n0 + 1 + r;
        if (node >= N_NODES) node -= N_NODES;
        *(float4*)&b_s[r][k4 * 4] = *(const float4*)(AB + (size_t)node * 128 + 64 + k4 * 4);
    }
    __syncthreads();

    const int row = t >> 2;
    const bool ok = row < nvalid;
    double ss = 0.0;
    if (ok) {
        const float* Ap = AB + (size_t)(n0 + row) * 128;   // L1-broadcast reads
        const int ebase = n0 * 16 + (t << 2);
        int4   c4 = *(const int4*)(indices + N_EDGES + ebase);
        float4 v4 = *(const float4*)(values + ebase);
        int   cols[4] = {c4.x, c4.y, c4.z, c4.w};
        float vv[4]   = {v4.x, v4.y, v4.z, v4.w};
        int   ii[4];
        bool  fb[4];
        bool  anyfb = false;
#pragma unroll
        for (int k = 0; k < 4; ++k) {
            int i = cols[k] - (n0 + 1);
            if (i < 0) i += N_NODES;
            fb[k] = (i >= 80);
            anyfb |= fb[k];
            ii[k] = fb[k] ? 0 : i;
        }
        float acc[4] = {0.f, 0.f, 0.f, 0.f};
#pragma unroll
        for (int q = 0; q < 16; ++q) {
            float4 a4  = *(const float4*)(Ap + q * 4);
            float4 wv4 = *(const float4*)&wv_s[q * 4];
            float4 w14 = *(const float4*)&w1_s[q * 4];
#pragma unroll
            for (int k = 0; k < 4; ++k) {
                float4 b4 = *(const float4*)&b_s[ii[k]][q * 4];
                float t0 = fmaf(wv4.x, vv[k], a4.x + b4.x);
                float t1 = fmaf(wv4.y, vv[k], a4.y + b4.y);
                float t2 = fmaf(wv4.z, vv[k], a4.z + b4.z);
                float t3 = fmaf(wv4.w, vv[k], a4.w + b4.w);
                acc[k] = fmaf(w14.x, fmaxf(t0, 0.f), acc[k]);
                acc[k] = fmaf(w14.y, fmaxf(t1, 0.f), acc[k]);
                acc[k] = fmaf(w14.z, fmaxf(t2, 0.f), acc[k]);
                acc[k] = fmaf(w14.w, fmaxf(t3, 0.f), acc[k]);
            }
        }
        if (anyfb) {            // never taken for this graph; correctness net
#pragma unroll
            for (int k = 0; k < 4; ++k) {
                if (fb[k]) {
                    const float* Bp = AB + (size_t)cols[k] * 128 + 64;
                    float a = 0.f;
                    for (int h = 0; h < 64; ++h) {
                        float th = fmaf(wv_s[h], vv[k], Ap[h] + Bp[h]);
                        a = fmaf(w1_s[h], fmaxf(th, 0.f), a);
                    }
                    acc[k] = a;
                }
            }
        }
        const float b1v = b1[0];
        float4 z4;
        z4.x = acc[0] + b1v; z4.y = acc[1] + b1v;
        z4.z = acc[2] + b1v; z4.w = acc[3] + b1v;
        *(float4*)(z + ebase) = z4;
        ss = (double)z4.x * z4.x + (double)z4.y * z4.y +
             (double)z4.z * z4.z + (double)z4.w * z4.w;
    }
    // deterministic wave shuffle reduce (fp64), then 4 partials -> block sum
#pragma unroll
    for (int off = 32; off > 0; off >>= 1) ss += __shfl_down(ss, off, 64);
    if ((t & 63) == 0) redw[t >> 6] = ss;
    __syncthreads();
    if (t == 0) partial[blockIdx.x] = (redw[0] + redw[1]) + (redw[2] + redw[3]);
}

// ---------------------------------------------------------------------------
// Kernel 3 (norm inlined into mask): every block performs the EXACT k_norm
// traversal over the 1563 partials (bit-identical nrm), then the mask body.
// ---------------------------------------------------------------------------
__global__ __launch_bounds__(256) void k_mask(const float* __restrict__ z,
                                              const float* __restrict__ gumbel,
                                              const double* __restrict__ partial,
                                              const int* __restrict__ temperature,
                                              float* __restrict__ out) {
    __shared__ double red[256];
    const int t = threadIdx.x;
    {
        double s = 0.0;
        for (int i = t; i < NBLK2; i += 256) s += partial[i];
        red[t] = s;
        __syncthreads();
#pragma unroll
        for (int off = 128; off > 0; off >>= 1) {
            if (t < off) red[t] += red[t + off];
            __syncthreads();
        }
    }
    const double nv = fmax(sqrt(red[0]), 1e-12);

    const int n = blockIdx.x * 256 + t;
    if (n >= N_NODES) return;
    const double inv_nv = 1.0 / nv;
    const double invT = 1.0 / (double)temperature[0];
    const float4* z4 = (const float4*)(z + (size_t)n * 16);
    const float4* g4 = (const float4*)(gumbel + (size_t)n * 16);
    double tl[16], y[16];
#pragma unroll
    for (int q = 0; q < 4; ++q) {
        float4 zv = z4[q];
        float4 gv = g4[q];
        tl[q * 4 + 0] = ((double)zv.x * inv_nv + (double)gv.x) * invT;
        tl[q * 4 + 1] = ((double)zv.y * inv_nv + (double)gv.y) * invT;
        tl[q * 4 + 2] = ((double)zv.z * inv_nv + (double)gv.z) * invT;
        tl[q * 4 + 3] = ((double)zv.w * inv_nv + (double)gv.w) * invT;
    }
    double m = tl[0];
#pragma unroll
    for (int i = 1; i < 16; ++i) m = fmax(m, tl[i]);
    double s = 0.0;
#pragma unroll
    for (int i = 0; i < 16; ++i) { y[i] = exp(tl[i] - m); s += y[i]; }
    const double inv_s = 1.0 / s;
#pragma unroll
    for (int i = 0; i < 16; ++i) y[i] *= inv_s;
    double thre = y[0];
#pragma unroll
    for (int i = 0; i < 16; ++i) {
        int c = 0, q = 0;
#pragma unroll
        for (int j = 0; j < 16; ++j) {
            c += (y[j] > y[i]) ? 1 : 0;
            q += (y[j] == y[i]) ? 1 : 0;
        }
        if (c <= 7 && 7 < c + q) thre = y[i];
    }
    float4* o4 = (float4*)(out + (size_t)n * 16);
#pragma unroll
    for (int qq = 0; qq < 4; ++qq) {
        float4 ov;
        ov.x = ((y[qq * 4 + 0] - thre + 1e-12) > 0.0) ? (float)y[qq * 4 + 0] : 0.f;
        ov.y = ((y[qq * 4 + 1] - thre + 1e-12) > 0.0) ? (float)y[qq * 4 + 1] : 0.f;
        ov.z = ((y[qq * 4 + 2] - thre + 1e-12) > 0.0) ? (float)y[qq * 4 + 2] : 0.f;
        ov.w = ((y[qq * 4 + 3] - thre + 1e-12) > 0.0) ? (float)y[qq * 4 + 3] : 0.f;
        o4[qq] = ov;
    }
}

// ---------------------------------------------------------------------------
extern "C" void kernel_launch(void* const* d_in, const int* in_sizes, int n_in,
                              void* d_out, int out_size, void* d_ws, size_t ws_size,
                              hipStream_t stream) {
    const float* feat    = (const float*)d_in[0];   // [N,64]
    const float* values  = (const float*)d_in[1];   // [E]
    const float* w0      = (const float*)d_in[2];   // [64,129]
    const float* b0      = (const float*)d_in[3];   // [64]
    const float* w1      = (const float*)d_in[4];   // [1,64]
    const float* b1      = (const float*)d_in[5];   // [1]
    const float* gumbel  = (const float*)d_in[6];   // [E]
    const int*   indices = (const int*)d_in[7];     // [2,E]
    const int*   temp    = (const int*)d_in[9];     // scalar
    float* out = (float*)d_out;

    // workspace: w0T 32KB | AB 51.2MB | z 6.4MB | partial (1563 doubles)
    float*  w0T     = (float*)d_ws;
    float*  AB      = (float*)((char*)d_ws + 64 * 128 * 4);
    float*  zbuf    = (float*)((char*)d_ws + 64 * 128 * 4 + (size_t)N_NODES * 128 * 4);
    double* partial = (double*)((char*)d_ws + 64 * 128 * 4 + (size_t)N_NODES * 128 * 4
                                + (size_t)N_EDGES * 4);

    k_prep<<<32, 256, 0, stream>>>(w0, w0T);
    k_ab  <<<NBLK2, 512, 0, stream>>>(feat, w0T, b0, AB);
    k_edge<<<NBLK2, 256, 0, stream>>>(AB, values, indices, w0, w1, b1, zbuf, partial);
    k_mask<<<(N_NODES + 255) / 256, 256, 0, stream>>>(zbuf, gumbel, partial, temp, out);
}